// Round 13
// baseline (276.662 us; speedup 1.0000x reference)
//
#include <hip/hip_runtime.h>
#include <math.h>

// ScoreFPELoss — fused per-sample pipeline (fp32), round 13.
// Identical to round 12 EXCEPT __launch_bounds__(512, 2) on kfused:
// round-12 counters showed VGPR_Count=128 (compiler's 4-wave/SIMD heuristic cap)
// with ~120 MB/dispatch of spill traffic (WRITE_SIZE). LDS (62 KB) caps us at
// 1 block/CU = 2 waves/SIMD regardless, so declaring (512,2) raises the VGPR
// cap to 256 at zero occupancy cost -> spill eliminated.
//
// Per sample (W1x = W1[0:64,:], w1t = W1[64,:]):
//   z1 = W1x^T x + t*w1t + b1 ; h1 = tanh(z1); a1 = 1-h1^2 ; q1 = a1.*w1t
//   z2 = W2^T h1 + b2         ; h2 = tanh(z2); a2 = 1-h2^2
//   s_t = (a2 .* (W2^T q1)) . w3sum
//   s  = W3^T h2 + b3 ;  y = 2s + x ;  r3[n] = sum_k W3[n,k] y[k]
//   u = C a2 ; v = C^T a1      (C = W2 .* (W1x^T W3^T), precomputed)
//   t2 = a2 .* (r3 - 2 h2 .* v) ; p = a1 .* (W2 t2 - 2 h1 .* u)
//   g  = s + W1x p ; out = mean_d | s_t - 0.5*beta*g_d |

#define Dd 64
#define Hh 512

// ---------------- KPRE: C/CT + transposes + w3sum (145 blocks) ----------------
__global__ __launch_bounds__(256) void kpre(const float* __restrict__ W1,
                                            const float* __restrict__ W3,
                                            const float* __restrict__ W2,
                                            float* __restrict__ C,
                                            float* __restrict__ CT,
                                            float* __restrict__ W2T,
                                            float* __restrict__ W1T,
                                            float* __restrict__ W3T,
                                            float* __restrict__ w3sum) {
  const int b = blockIdx.x, tid = threadIdx.x;
  __shared__ float sA[64][68];
  __shared__ float sB[64][68];
  __shared__ float sT[64][65];
  if (b < 64) {
    const int bj = (b & 7) * 64, bl = (b >> 3) * 64;
    for (int q = 0; q < 16; q++) {
      int idx = tid + q * 256, i = idx >> 6, j = idx & 63;
      sA[i][j] = W1[i * Hh + bj + j];
    }
    for (int q = 0; q < 16; q++) {
      int idx = tid + q * 256, l = idx >> 6, i = idx & 63;
      sB[i][l] = W3[(bl + l) * Dd + i];
    }
    __syncthreads();
    const int tj = (tid >> 4) << 2, tl = (tid & 15) << 2;
    float acc[4][4] = {};
#pragma unroll 8
    for (int i = 0; i < 64; i++) {
      float4 a = *(const float4*)&sA[i][tj];
      float4 bb = *(const float4*)&sB[i][tl];
      float ar[4] = {a.x, a.y, a.z, a.w};
      float br[4] = {bb.x, bb.y, bb.z, bb.w};
#pragma unroll
      for (int r = 0; r < 4; r++)
#pragma unroll
        for (int c = 0; c < 4; c++) acc[r][c] += ar[r] * br[c];
    }
    float cv[4][4];
#pragma unroll
    for (int r = 0; r < 4; r++)
#pragma unroll
      for (int c = 0; c < 4; c++)
        cv[r][c] = W2[(bj + tj + r) * Hh + bl + tl + c] * acc[r][c];
#pragma unroll
    for (int r = 0; r < 4; r++) {
      float4 o = {cv[r][0], cv[r][1], cv[r][2], cv[r][3]};
      *(float4*)&C[(bj + tj + r) * Hh + bl + tl] = o;
    }
#pragma unroll
    for (int c = 0; c < 4; c++) {
      float4 o = {cv[0][c], cv[1][c], cv[2][c], cv[3][c]};
      *(float4*)&CT[(bl + tl + c) * Hh + bj + tj] = o;
    }
  } else if (b < 128) {
    const int t = b - 64, r0 = (t & 7) * 64, c0 = (t >> 3) * 64;
    for (int q = 0; q < 16; q++) {
      int idx = tid + q * 256, i = idx >> 6, j = idx & 63;
      sT[i][j] = W2[(r0 + i) * Hh + c0 + j];
    }
    __syncthreads();
    for (int q = 0; q < 16; q++) {
      int idx = tid + q * 256, i = idx >> 6, j = idx & 63;
      W2T[(c0 + i) * Hh + r0 + j] = sT[j][i];
    }
  } else if (b < 136) {
    const int t = b - 128, c0 = t * 64;
    for (int q = 0; q < 16; q++) {
      int idx = tid + q * 256, i = idx >> 6, j = idx & 63;
      sT[i][j] = W1[i * Hh + c0 + j];
    }
    __syncthreads();
    for (int q = 0; q < 16; q++) {
      int idx = tid + q * 256, i = idx >> 6, j = idx & 63;
      W1T[(c0 + i) * Dd + j] = sT[j][i];
    }
  } else if (b < 144) {
    const int t = b - 136, r0 = t * 64;
    for (int q = 0; q < 16; q++) {
      int idx = tid + q * 256, i = idx >> 6, j = idx & 63;
      sT[i][j] = W3[(r0 + i) * Dd + j];
    }
    __syncthreads();
    for (int q = 0; q < 16; q++) {
      int idx = tid + q * 256, i = idx >> 6, j = idx & 63;
      W3T[i * Hh + r0 + j] = sT[j][i];
    }
  } else {
#pragma unroll
    for (int r = 0; r < 2; r++) {
      int n = tid + r * 256;
      float sacc = 0.f;
#pragma unroll 4
      for (int k4 = 0; k4 < 16; k4++) {
        float4 w = *(const float4*)&W3[n * Dd + k4 * 4];
        sacc += w.x; sacc += w.y; sacc += w.z; sacc += w.w;
      }
      w3sum[n] = sacc;
    }
  }
}

// load 4 named float4 (16 consecutive floats) from row pointer P at offset kb
#define LD4(P, kb)                                   \
  float4 w0 = *(const float4*)&(P)[(kb)];            \
  float4 w1 = *(const float4*)&(P)[(kb) + 4];        \
  float4 w2 = *(const float4*)&(P)[(kb) + 8];        \
  float4 w3 = *(const float4*)&(P)[(kb) + 12];

#define G16(M, kb)                                                        \
  M(w0.x, (kb) + 0) M(w0.y, (kb) + 1) M(w0.z, (kb) + 2) M(w0.w, (kb) + 3) \
  M(w1.x, (kb) + 4) M(w1.y, (kb) + 5) M(w1.z, (kb) + 6) M(w1.w, (kb) + 7) \
  M(w2.x, (kb) + 8) M(w2.y, (kb) + 9) M(w2.z, (kb) + 10) M(w2.w, (kb) + 11) \
  M(w3.x, (kb) + 12) M(w3.y, (kb) + 13) M(w3.z, (kb) + 14) M(w3.w, (kb) + 15)

// ---------------- KFUSED: 4 samples/block, 512 thr, VGPR cap 256 ----------------
__global__ __launch_bounds__(512, 2) void kfused(const float* __restrict__ X,
                                                 const float* __restrict__ tt,
                                                 const float* __restrict__ beta,
                                                 const float* __restrict__ W1,
                                                 const float* __restrict__ b1,
                                                 const float* __restrict__ W2,
                                                 const float* __restrict__ b2,
                                                 const float* __restrict__ W3,
                                                 const float* __restrict__ b3,
                                                 const float* __restrict__ C,
                                                 const float* __restrict__ CT,
                                                 const float* __restrict__ W2T,
                                                 const float* __restrict__ W1T,
                                                 const float* __restrict__ W3T,
                                                 const float* __restrict__ w3sum,
                                                 float* __restrict__ out) {
  __shared__ float xs[Dd * 4], ys[Dd * 4];
  __shared__ float h1s[Hh * 4], a1s[Hh * 4], q1s[Hh * 4];
  __shared__ float h2s[Hh * 4], a2s[Hh * 4], t2s[Hh * 4], ps[Hh * 4];
  __shared__ float sts[4], tb[4], bbv[4], red[32];
  __shared__ float ph[512];  // [ss][half][dd]

  const int tid = threadIdx.x;
  const int s0 = blockIdx.x * 4;
  const int n0 = tid;
  const int dd = tid & 63;
  const int half = (tid >> 6) & 1;
  const int ss = tid >> 7;

  // ---- Stage A ----
  if (tid < 256) {
    int sA = tid >> 6, dA = tid & 63;
    xs[dA * 4 + sA] = X[(s0 + sA) * Dd + dA];
  }
  if (tid < 4) tb[tid] = tt[s0 + tid];
  else if (tid < 8) bbv[tid - 4] = beta[s0 + tid - 4];
  __syncthreads();

  // ---- Stage B: layer 1 (W1T row n0, K=64) ----
  {
    float a0 = 0.f, a1v = 0.f, a2v = 0.f, a3v = 0.f;
    const float* Wr = &W1T[n0 * Dd];
#define FMB(wc, kk) { float4 xv = *(const float4*)&xs[(kk) * 4]; \
    a0 += (wc) * xv.x; a1v += (wc) * xv.y; a2v += (wc) * xv.z; a3v += (wc) * xv.w; }
#pragma unroll
    for (int k0 = 0; k0 < 64; k0 += 16) {
      LD4(Wr, k0)
      G16(FMB, k0)
    }
#undef FMB
    float wt = W1[Dd * Hh + n0], bc = b1[n0];
    float acc[4] = {a0, a1v, a2v, a3v};
    float4 hv, av, qv;
#pragma unroll
    for (int s = 0; s < 4; s++) {
      float z = acc[s] + tb[s] * wt + bc;
      float h = tanhf(z);
      float a = 1.f - h * h;
      ((float*)&hv)[s] = h; ((float*)&av)[s] = a; ((float*)&qv)[s] = a * wt;
    }
    *(float4*)&h1s[n0 * 4] = hv;
    *(float4*)&a1s[n0 * 4] = av;
    *(float4*)&q1s[n0 * 4] = qv;
  }
  __syncthreads();

  // ---- Stage C: layer 2 + s_t partials (W2T row n0, K=512, dual acc) ----
  {
    float b0 = 0.f, b1a = 0.f, b2a = 0.f, b3a = 0.f;
    float c0a = 0.f, c1a = 0.f, c2a = 0.f, c3a = 0.f;
    const float* Wr = &W2T[n0 * Hh];
#define FMC(wc, kk) { float4 hv_ = *(const float4*)&h1s[(kk) * 4]; \
    float4 qv_ = *(const float4*)&q1s[(kk) * 4]; \
    b0 += (wc) * hv_.x; b1a += (wc) * hv_.y; b2a += (wc) * hv_.z; b3a += (wc) * hv_.w; \
    c0a += (wc) * qv_.x; c1a += (wc) * qv_.y; c2a += (wc) * qv_.z; c3a += (wc) * qv_.w; }
#pragma unroll 2
    for (int k0 = 0; k0 < 512; k0 += 16) {
      LD4(Wr, k0)
      G16(FMC, k0)
    }
#undef FMC
    float bc = b2[n0], wc = w3sum[n0];
    float acc1[4] = {b0, b1a, b2a, b3a};
    float acc2[4] = {c0a, c1a, c2a, c3a};
    float stp[4];
    float4 hv, av;
#pragma unroll
    for (int s = 0; s < 4; s++) {
      float z = acc1[s] + bc;
      float h = tanhf(z);
      float a = 1.f - h * h;
      ((float*)&hv)[s] = h; ((float*)&av)[s] = a;
      stp[s] = a * acc2[s] * wc;
    }
    *(float4*)&h2s[n0 * 4] = hv;
    *(float4*)&a2s[n0 * 4] = av;
#pragma unroll
    for (int off = 1; off < 64; off <<= 1)
#pragma unroll
      for (int s = 0; s < 4; s++) stp[s] += __shfl_xor(stp[s], off, 64);
    if (dd == 0)
#pragma unroll
      for (int s = 0; s < 4; s++) red[(tid >> 6) * 4 + s] = stp[s];
  }
  __syncthreads();
  if (tid < 4) {
    float t = 0.f;
#pragma unroll
    for (int w = 0; w < 8; w++) t += red[w * 4 + tid];
    sts[tid] = t;
  }

  // ---- Stage D: s = W3^T h2 + b3 (W3T row dd, half-split) ----
  {
    float sacc = half ? 0.f : b3[dd];
    const int hb = half * 256;
    const float* Wr = &W3T[dd * Hh + hb];
#define FMD(wc, ll) sacc += (wc) * h2s[(hb + (ll)) * 4 + ss];
#pragma unroll 2
    for (int c0 = 0; c0 < 256; c0 += 16) {
      LD4(Wr, c0)
      G16(FMD, c0)
    }
#undef FMD
    ph[tid] = sacc;
  }
  __syncthreads();
  float sval = 0.f;
  if (half == 0) {
    sval = ph[ss * 128 + dd] + ph[ss * 128 + 64 + dd];
    ys[dd * 4 + ss] = 2.f * sval + xs[dd * 4 + ss];
  }
  __syncthreads();

  // ---- Stage E: r3 (W3 row n0); u = C a2, v = C^T a1 (row streams); t2 ----
  float u0 = 0.f, u1a = 0.f, u2a = 0.f, u3a = 0.f;
  {
    float r0 = 0.f, r1a = 0.f, r2a = 0.f, r3a = 0.f;
    const float* Wr = &W3[n0 * Dd];
#define FME(wc, kk) { float4 yv = *(const float4*)&ys[(kk) * 4]; \
    r0 += (wc) * yv.x; r1a += (wc) * yv.y; r2a += (wc) * yv.z; r3a += (wc) * yv.w; }
#pragma unroll
    for (int k0 = 0; k0 < 64; k0 += 16) {
      LD4(Wr, k0)
      G16(FME, k0)
    }
#undef FME
    float v0 = 0.f, v1a = 0.f, v2a = 0.f, v3a = 0.f;
    const float* Cr = &C[n0 * Hh];
    const float* Tr = &CT[n0 * Hh];
#define FMU(wc, kk) { float4 av_ = *(const float4*)&a2s[(kk) * 4]; \
    u0 += (wc) * av_.x; u1a += (wc) * av_.y; u2a += (wc) * av_.z; u3a += (wc) * av_.w; }
#define FMV(wc, kk) { float4 av_ = *(const float4*)&a1s[(kk) * 4]; \
    v0 += (wc) * av_.x; v1a += (wc) * av_.y; v2a += (wc) * av_.z; v3a += (wc) * av_.w; }
#pragma unroll 2
    for (int k0 = 0; k0 < 512; k0 += 8) {
      float4 cu0 = *(const float4*)&Cr[k0];
      float4 cu1 = *(const float4*)&Cr[k0 + 4];
      float4 ct0 = *(const float4*)&Tr[k0];
      float4 ct1 = *(const float4*)&Tr[k0 + 4];
      FMU(cu0.x, k0 + 0) FMU(cu0.y, k0 + 1) FMU(cu0.z, k0 + 2) FMU(cu0.w, k0 + 3)
      FMU(cu1.x, k0 + 4) FMU(cu1.y, k0 + 5) FMU(cu1.z, k0 + 6) FMU(cu1.w, k0 + 7)
      FMV(ct0.x, k0 + 0) FMV(ct0.y, k0 + 1) FMV(ct0.z, k0 + 2) FMV(ct0.w, k0 + 3)
      FMV(ct1.x, k0 + 4) FMV(ct1.y, k0 + 5) FMV(ct1.z, k0 + 6) FMV(ct1.w, k0 + 7)
    }
#undef FMU
#undef FMV
    float4 a2r = *(const float4*)&a2s[n0 * 4];
    float4 h2r = *(const float4*)&h2s[n0 * 4];
    float4 t2v;
    t2v.x = a2r.x * (r0 - 2.f * h2r.x * v0);
    t2v.y = a2r.y * (r1a - 2.f * h2r.y * v1a);
    t2v.z = a2r.z * (r2a - 2.f * h2r.z * v2a);
    t2v.w = a2r.w * (r3a - 2.f * h2r.w * v3a);
    *(float4*)&t2s[n0 * 4] = t2v;
  }
  __syncthreads();

  // ---- Stage F: p = a1 .* (W2 t2 - 2 h1 .* u) (W2 row n0) ----
  {
    float p0 = 0.f, p1a = 0.f, p2a = 0.f, p3a = 0.f;
    const float* Wr = &W2[n0 * Hh];
#define FMF(wc, kk) { float4 tv = *(const float4*)&t2s[(kk) * 4]; \
    p0 += (wc) * tv.x; p1a += (wc) * tv.y; p2a += (wc) * tv.z; p3a += (wc) * tv.w; }
#pragma unroll 2
    for (int k0 = 0; k0 < 512; k0 += 16) {
      LD4(Wr, k0)
      G16(FMF, k0)
    }
#undef FMF
    float4 a1r = *(const float4*)&a1s[n0 * 4];
    float4 h1r = *(const float4*)&h1s[n0 * 4];
    float4 pv;
    pv.x = a1r.x * (p0 - 2.f * h1r.x * u0);
    pv.y = a1r.y * (p1a - 2.f * h1r.y * u1a);
    pv.z = a1r.z * (p2a - 2.f * h1r.z * u2a);
    pv.w = a1r.w * (p3a - 2.f * h1r.w * u3a);
    *(float4*)&ps[n0 * 4] = pv;
  }
  __syncthreads();

  // ---- Stage G: g = s + W1x p (W1 row dd, half-split); loss ----
  {
    float gq = (half == 0) ? sval : 0.f;
    const int jb = half * 256;
    const float* Wr = &W1[dd * Hh + jb];
#define FMG(wc, jj) gq += (wc) * ps[(jb + (jj)) * 4 + ss];
#pragma unroll 2
    for (int c0 = 0; c0 < 256; c0 += 16) {
      LD4(Wr, c0)
      G16(FMG, c0)
    }
#undef FMG
    ph[tid] = gq;
  }
  __syncthreads();
  if (half == 0) {
    float g = ph[ss * 128 + dd] + ph[ss * 128 + 64 + dd];
    float e = fabsf(sts[ss] - 0.5f * bbv[ss] * g);
#pragma unroll
    for (int off = 32; off; off >>= 1) e += __shfl_down(e, off, 64);
    if (dd == 0) out[s0 + ss] = e * (1.f / 64.f);
  }
}

extern "C" void kernel_launch(void* const* d_in, const int* in_sizes, int n_in,
                              void* d_out, int out_size, void* d_ws, size_t ws_size,
                              hipStream_t stream) {
  const float* X    = (const float*)d_in[0];
  const float* tt   = (const float*)d_in[1];
  const float* beta = (const float*)d_in[2];
  const float* W1   = (const float*)d_in[3];
  const float* b1   = (const float*)d_in[4];
  const float* W2   = (const float*)d_in[5];
  const float* b2   = (const float*)d_in[6];
  const float* W3   = (const float*)d_in[7];
  const float* b3   = (const float*)d_in[8];
  float* out = (float*)d_out;

  float* ws   = (float*)d_ws;
  float* C    = ws;              // 512*512
  float* CT   = C + 262144;      // 512*512
  float* W2T  = CT + 262144;     // 512*512
  float* W1T  = W2T + 262144;    // 512*64
  float* W3T  = W1T + 32768;     // 64*512
  float* w3s  = W3T + 32768;     // 512

  kpre<<<145, 256, 0, stream>>>(W1, W3, W2, C, CT, W2T, W1T, W3T, w3s);
  kfused<<<256, 512, 0, stream>>>(X, tt, beta, W1, b1, W2, b2, W3, b3,
                                  C, CT, W2T, W1T, W3T, w3s, out);
}

// Round 14
// 236.426 us; speedup vs baseline: 1.1702x; 1.1702x over previous
//
#include <hip/hip_runtime.h>
#include <math.h>

// ScoreFPELoss — fused per-sample pipeline (fp32), round 14.
// Identical to round 13 EXCEPT all K-loops are #pragma unroll 1:
// rounds 12/13 showed VGPR=128 + ~120 MB/dispatch spill traffic (WRITE_SIZE)
// regardless of __launch_bounds__ — the outer unrolls let the scheduler hoist
// ~200 live values. Unroll 1 keeps 4 global f4 loads in flight (LD4) with a
// ~60-90 VGPR window -> no spill. FP accumulation order unchanged.
//
// Per sample (W1x = W1[0:64,:], w1t = W1[64,:]):
//   z1 = W1x^T x + t*w1t + b1 ; h1 = tanh(z1); a1 = 1-h1^2 ; q1 = a1.*w1t
//   z2 = W2^T h1 + b2         ; h2 = tanh(z2); a2 = 1-h2^2
//   s_t = (a2 .* (W2^T q1)) . w3sum
//   s  = W3^T h2 + b3 ;  y = 2s + x ;  r3[n] = sum_k W3[n,k] y[k]
//   u = C a2 ; v = C^T a1      (C = W2 .* (W1x^T W3^T), precomputed)
//   t2 = a2 .* (r3 - 2 h2 .* v) ; p = a1 .* (W2 t2 - 2 h1 .* u)
//   g  = s + W1x p ; out = mean_d | s_t - 0.5*beta*g_d |

#define Dd 64
#define Hh 512

// ---------------- KPRE: C/CT + transposes + w3sum (145 blocks) ----------------
__global__ __launch_bounds__(256) void kpre(const float* __restrict__ W1,
                                            const float* __restrict__ W3,
                                            const float* __restrict__ W2,
                                            float* __restrict__ C,
                                            float* __restrict__ CT,
                                            float* __restrict__ W2T,
                                            float* __restrict__ W1T,
                                            float* __restrict__ W3T,
                                            float* __restrict__ w3sum) {
  const int b = blockIdx.x, tid = threadIdx.x;
  __shared__ float sA[64][68];
  __shared__ float sB[64][68];
  __shared__ float sT[64][65];
  if (b < 64) {
    const int bj = (b & 7) * 64, bl = (b >> 3) * 64;
    for (int q = 0; q < 16; q++) {
      int idx = tid + q * 256, i = idx >> 6, j = idx & 63;
      sA[i][j] = W1[i * Hh + bj + j];
    }
    for (int q = 0; q < 16; q++) {
      int idx = tid + q * 256, l = idx >> 6, i = idx & 63;
      sB[i][l] = W3[(bl + l) * Dd + i];
    }
    __syncthreads();
    const int tj = (tid >> 4) << 2, tl = (tid & 15) << 2;
    float acc[4][4] = {};
#pragma unroll 8
    for (int i = 0; i < 64; i++) {
      float4 a = *(const float4*)&sA[i][tj];
      float4 bb = *(const float4*)&sB[i][tl];
      float ar[4] = {a.x, a.y, a.z, a.w};
      float br[4] = {bb.x, bb.y, bb.z, bb.w};
#pragma unroll
      for (int r = 0; r < 4; r++)
#pragma unroll
        for (int c = 0; c < 4; c++) acc[r][c] += ar[r] * br[c];
    }
    float cv[4][4];
#pragma unroll
    for (int r = 0; r < 4; r++)
#pragma unroll
      for (int c = 0; c < 4; c++)
        cv[r][c] = W2[(bj + tj + r) * Hh + bl + tl + c] * acc[r][c];
#pragma unroll
    for (int r = 0; r < 4; r++) {
      float4 o = {cv[r][0], cv[r][1], cv[r][2], cv[r][3]};
      *(float4*)&C[(bj + tj + r) * Hh + bl + tl] = o;
    }
#pragma unroll
    for (int c = 0; c < 4; c++) {
      float4 o = {cv[0][c], cv[1][c], cv[2][c], cv[3][c]};
      *(float4*)&CT[(bl + tl + c) * Hh + bj + tj] = o;
    }
  } else if (b < 128) {
    const int t = b - 64, r0 = (t & 7) * 64, c0 = (t >> 3) * 64;
    for (int q = 0; q < 16; q++) {
      int idx = tid + q * 256, i = idx >> 6, j = idx & 63;
      sT[i][j] = W2[(r0 + i) * Hh + c0 + j];
    }
    __syncthreads();
    for (int q = 0; q < 16; q++) {
      int idx = tid + q * 256, i = idx >> 6, j = idx & 63;
      W2T[(c0 + i) * Hh + r0 + j] = sT[j][i];
    }
  } else if (b < 136) {
    const int t = b - 128, c0 = t * 64;
    for (int q = 0; q < 16; q++) {
      int idx = tid + q * 256, i = idx >> 6, j = idx & 63;
      sT[i][j] = W1[i * Hh + c0 + j];
    }
    __syncthreads();
    for (int q = 0; q < 16; q++) {
      int idx = tid + q * 256, i = idx >> 6, j = idx & 63;
      W1T[(c0 + i) * Dd + j] = sT[j][i];
    }
  } else if (b < 144) {
    const int t = b - 136, r0 = t * 64;
    for (int q = 0; q < 16; q++) {
      int idx = tid + q * 256, i = idx >> 6, j = idx & 63;
      sT[i][j] = W3[(r0 + i) * Dd + j];
    }
    __syncthreads();
    for (int q = 0; q < 16; q++) {
      int idx = tid + q * 256, i = idx >> 6, j = idx & 63;
      W3T[i * Hh + r0 + j] = sT[j][i];
    }
  } else {
#pragma unroll
    for (int r = 0; r < 2; r++) {
      int n = tid + r * 256;
      float sacc = 0.f;
#pragma unroll 4
      for (int k4 = 0; k4 < 16; k4++) {
        float4 w = *(const float4*)&W3[n * Dd + k4 * 4];
        sacc += w.x; sacc += w.y; sacc += w.z; sacc += w.w;
      }
      w3sum[n] = sacc;
    }
  }
}

// load 4 named float4 (16 consecutive floats) from row pointer P at offset kb
#define LD4(P, kb)                                   \
  float4 w0 = *(const float4*)&(P)[(kb)];            \
  float4 w1 = *(const float4*)&(P)[(kb) + 4];        \
  float4 w2 = *(const float4*)&(P)[(kb) + 8];        \
  float4 w3 = *(const float4*)&(P)[(kb) + 12];

#define G16(M, kb)                                                        \
  M(w0.x, (kb) + 0) M(w0.y, (kb) + 1) M(w0.z, (kb) + 2) M(w0.w, (kb) + 3) \
  M(w1.x, (kb) + 4) M(w1.y, (kb) + 5) M(w1.z, (kb) + 6) M(w1.w, (kb) + 7) \
  M(w2.x, (kb) + 8) M(w2.y, (kb) + 9) M(w2.z, (kb) + 10) M(w2.w, (kb) + 11) \
  M(w3.x, (kb) + 12) M(w3.y, (kb) + 13) M(w3.z, (kb) + 14) M(w3.w, (kb) + 15)

// ---------------- KFUSED: 4 samples/block, 512 thr, unroll-1 K loops ----------------
__global__ __launch_bounds__(512, 2) void kfused(const float* __restrict__ X,
                                                 const float* __restrict__ tt,
                                                 const float* __restrict__ beta,
                                                 const float* __restrict__ W1,
                                                 const float* __restrict__ b1,
                                                 const float* __restrict__ W2,
                                                 const float* __restrict__ b2,
                                                 const float* __restrict__ W3,
                                                 const float* __restrict__ b3,
                                                 const float* __restrict__ C,
                                                 const float* __restrict__ CT,
                                                 const float* __restrict__ W2T,
                                                 const float* __restrict__ W1T,
                                                 const float* __restrict__ W3T,
                                                 const float* __restrict__ w3sum,
                                                 float* __restrict__ out) {
  __shared__ float xs[Dd * 4], ys[Dd * 4];
  __shared__ float h1s[Hh * 4], a1s[Hh * 4], q1s[Hh * 4];
  __shared__ float h2s[Hh * 4], a2s[Hh * 4], t2s[Hh * 4], ps[Hh * 4];
  __shared__ float sts[4], tb[4], bbv[4], red[32];
  __shared__ float ph[512];  // [ss][half][dd]

  const int tid = threadIdx.x;
  const int s0 = blockIdx.x * 4;
  const int n0 = tid;
  const int dd = tid & 63;
  const int half = (tid >> 6) & 1;
  const int ss = tid >> 7;

  // ---- Stage A ----
  if (tid < 256) {
    int sA = tid >> 6, dA = tid & 63;
    xs[dA * 4 + sA] = X[(s0 + sA) * Dd + dA];
  }
  if (tid < 4) tb[tid] = tt[s0 + tid];
  else if (tid < 8) bbv[tid - 4] = beta[s0 + tid - 4];
  __syncthreads();

  // ---- Stage B: layer 1 (W1T row n0, K=64) ----
  {
    float a0 = 0.f, a1v = 0.f, a2v = 0.f, a3v = 0.f;
    const float* Wr = &W1T[n0 * Dd];
#define FMB(wc, kk) { float4 xv = *(const float4*)&xs[(kk) * 4]; \
    a0 += (wc) * xv.x; a1v += (wc) * xv.y; a2v += (wc) * xv.z; a3v += (wc) * xv.w; }
#pragma unroll 1
    for (int k0 = 0; k0 < 64; k0 += 16) {
      LD4(Wr, k0)
      G16(FMB, k0)
    }
#undef FMB
    float wt = W1[Dd * Hh + n0], bc = b1[n0];
    float acc[4] = {a0, a1v, a2v, a3v};
    float4 hv, av, qv;
#pragma unroll
    for (int s = 0; s < 4; s++) {
      float z = acc[s] + tb[s] * wt + bc;
      float h = tanhf(z);
      float a = 1.f - h * h;
      ((float*)&hv)[s] = h; ((float*)&av)[s] = a; ((float*)&qv)[s] = a * wt;
    }
    *(float4*)&h1s[n0 * 4] = hv;
    *(float4*)&a1s[n0 * 4] = av;
    *(float4*)&q1s[n0 * 4] = qv;
  }
  __syncthreads();

  // ---- Stage C: layer 2 + s_t partials (W2T row n0, K=512, dual acc) ----
  {
    float b0 = 0.f, b1a = 0.f, b2a = 0.f, b3a = 0.f;
    float c0a = 0.f, c1a = 0.f, c2a = 0.f, c3a = 0.f;
    const float* Wr = &W2T[n0 * Hh];
#define FMC(wc, kk) { float4 hv_ = *(const float4*)&h1s[(kk) * 4]; \
    float4 qv_ = *(const float4*)&q1s[(kk) * 4]; \
    b0 += (wc) * hv_.x; b1a += (wc) * hv_.y; b2a += (wc) * hv_.z; b3a += (wc) * hv_.w; \
    c0a += (wc) * qv_.x; c1a += (wc) * qv_.y; c2a += (wc) * qv_.z; c3a += (wc) * qv_.w; }
#pragma unroll 1
    for (int k0 = 0; k0 < 512; k0 += 16) {
      LD4(Wr, k0)
      G16(FMC, k0)
    }
#undef FMC
    float bc = b2[n0], wc = w3sum[n0];
    float acc1[4] = {b0, b1a, b2a, b3a};
    float acc2[4] = {c0a, c1a, c2a, c3a};
    float stp[4];
    float4 hv, av;
#pragma unroll
    for (int s = 0; s < 4; s++) {
      float z = acc1[s] + bc;
      float h = tanhf(z);
      float a = 1.f - h * h;
      ((float*)&hv)[s] = h; ((float*)&av)[s] = a;
      stp[s] = a * acc2[s] * wc;
    }
    *(float4*)&h2s[n0 * 4] = hv;
    *(float4*)&a2s[n0 * 4] = av;
#pragma unroll
    for (int off = 1; off < 64; off <<= 1)
#pragma unroll
      for (int s = 0; s < 4; s++) stp[s] += __shfl_xor(stp[s], off, 64);
    if (dd == 0)
#pragma unroll
      for (int s = 0; s < 4; s++) red[(tid >> 6) * 4 + s] = stp[s];
  }
  __syncthreads();
  if (tid < 4) {
    float t = 0.f;
#pragma unroll
    for (int w = 0; w < 8; w++) t += red[w * 4 + tid];
    sts[tid] = t;
  }

  // ---- Stage D: s = W3^T h2 + b3 (W3T row dd, half-split) ----
  {
    float sacc = half ? 0.f : b3[dd];
    const int hb = half * 256;
    const float* Wr = &W3T[dd * Hh + hb];
#define FMD(wc, ll) sacc += (wc) * h2s[(hb + (ll)) * 4 + ss];
#pragma unroll 1
    for (int c0 = 0; c0 < 256; c0 += 16) {
      LD4(Wr, c0)
      G16(FMD, c0)
    }
#undef FMD
    ph[tid] = sacc;
  }
  __syncthreads();
  float sval = 0.f;
  if (half == 0) {
    sval = ph[ss * 128 + dd] + ph[ss * 128 + 64 + dd];
    ys[dd * 4 + ss] = 2.f * sval + xs[dd * 4 + ss];
  }
  __syncthreads();

  // ---- Stage E: r3 (W3 row n0); u = C a2, v = C^T a1 (row streams); t2 ----
  float u0 = 0.f, u1a = 0.f, u2a = 0.f, u3a = 0.f;
  {
    float r0 = 0.f, r1a = 0.f, r2a = 0.f, r3a = 0.f;
    const float* Wr = &W3[n0 * Dd];
#define FME(wc, kk) { float4 yv = *(const float4*)&ys[(kk) * 4]; \
    r0 += (wc) * yv.x; r1a += (wc) * yv.y; r2a += (wc) * yv.z; r3a += (wc) * yv.w; }
#pragma unroll 1
    for (int k0 = 0; k0 < 64; k0 += 16) {
      LD4(Wr, k0)
      G16(FME, k0)
    }
#undef FME
    float v0 = 0.f, v1a = 0.f, v2a = 0.f, v3a = 0.f;
    const float* Cr = &C[n0 * Hh];
    const float* Tr = &CT[n0 * Hh];
#define FMU(wc, kk) { float4 av_ = *(const float4*)&a2s[(kk) * 4]; \
    u0 += (wc) * av_.x; u1a += (wc) * av_.y; u2a += (wc) * av_.z; u3a += (wc) * av_.w; }
#define FMV(wc, kk) { float4 av_ = *(const float4*)&a1s[(kk) * 4]; \
    v0 += (wc) * av_.x; v1a += (wc) * av_.y; v2a += (wc) * av_.z; v3a += (wc) * av_.w; }
#pragma unroll 1
    for (int k0 = 0; k0 < 512; k0 += 8) {
      float4 cu0 = *(const float4*)&Cr[k0];
      float4 cu1 = *(const float4*)&Cr[k0 + 4];
      float4 ct0 = *(const float4*)&Tr[k0];
      float4 ct1 = *(const float4*)&Tr[k0 + 4];
      FMU(cu0.x, k0 + 0) FMU(cu0.y, k0 + 1) FMU(cu0.z, k0 + 2) FMU(cu0.w, k0 + 3)
      FMU(cu1.x, k0 + 4) FMU(cu1.y, k0 + 5) FMU(cu1.z, k0 + 6) FMU(cu1.w, k0 + 7)
      FMV(ct0.x, k0 + 0) FMV(ct0.y, k0 + 1) FMV(ct0.z, k0 + 2) FMV(ct0.w, k0 + 3)
      FMV(ct1.x, k0 + 4) FMV(ct1.y, k0 + 5) FMV(ct1.z, k0 + 6) FMV(ct1.w, k0 + 7)
    }
#undef FMU
#undef FMV
    float4 a2r = *(const float4*)&a2s[n0 * 4];
    float4 h2r = *(const float4*)&h2s[n0 * 4];
    float4 t2v;
    t2v.x = a2r.x * (r0 - 2.f * h2r.x * v0);
    t2v.y = a2r.y * (r1a - 2.f * h2r.y * v1a);
    t2v.z = a2r.z * (r2a - 2.f * h2r.z * v2a);
    t2v.w = a2r.w * (r3a - 2.f * h2r.w * v3a);
    *(float4*)&t2s[n0 * 4] = t2v;
  }
  __syncthreads();

  // ---- Stage F: p = a1 .* (W2 t2 - 2 h1 .* u) (W2 row n0) ----
  {
    float p0 = 0.f, p1a = 0.f, p2a = 0.f, p3a = 0.f;
    const float* Wr = &W2[n0 * Hh];
#define FMF(wc, kk) { float4 tv = *(const float4*)&t2s[(kk) * 4]; \
    p0 += (wc) * tv.x; p1a += (wc) * tv.y; p2a += (wc) * tv.z; p3a += (wc) * tv.w; }
#pragma unroll 1
    for (int k0 = 0; k0 < 512; k0 += 16) {
      LD4(Wr, k0)
      G16(FMF, k0)
    }
#undef FMF
    float4 a1r = *(const float4*)&a1s[n0 * 4];
    float4 h1r = *(const float4*)&h1s[n0 * 4];
    float4 pv;
    pv.x = a1r.x * (p0 - 2.f * h1r.x * u0);
    pv.y = a1r.y * (p1a - 2.f * h1r.y * u1a);
    pv.z = a1r.z * (p2a - 2.f * h1r.z * u2a);
    pv.w = a1r.w * (p3a - 2.f * h1r.w * u3a);
    *(float4*)&ps[n0 * 4] = pv;
  }
  __syncthreads();

  // ---- Stage G: g = s + W1x p (W1 row dd, half-split); loss ----
  {
    float gq = (half == 0) ? sval : 0.f;
    const int jb = half * 256;
    const float* Wr = &W1[dd * Hh + jb];
#define FMG(wc, jj) gq += (wc) * ps[(jb + (jj)) * 4 + ss];
#pragma unroll 1
    for (int c0 = 0; c0 < 256; c0 += 16) {
      LD4(Wr, c0)
      G16(FMG, c0)
    }
#undef FMG
    ph[tid] = gq;
  }
  __syncthreads();
  if (half == 0) {
    float g = ph[ss * 128 + dd] + ph[ss * 128 + 64 + dd];
    float e = fabsf(sts[ss] - 0.5f * bbv[ss] * g);
#pragma unroll
    for (int off = 32; off; off >>= 1) e += __shfl_down(e, off, 64);
    if (dd == 0) out[s0 + ss] = e * (1.f / 64.f);
  }
}

extern "C" void kernel_launch(void* const* d_in, const int* in_sizes, int n_in,
                              void* d_out, int out_size, void* d_ws, size_t ws_size,
                              hipStream_t stream) {
  const float* X    = (const float*)d_in[0];
  const float* tt   = (const float*)d_in[1];
  const float* beta = (const float*)d_in[2];
  const float* W1   = (const float*)d_in[3];
  const float* b1   = (const float*)d_in[4];
  const float* W2   = (const float*)d_in[5];
  const float* b2   = (const float*)d_in[6];
  const float* W3   = (const float*)d_in[7];
  const float* b3   = (const float*)d_in[8];
  float* out = (float*)d_out;

  float* ws   = (float*)d_ws;
  float* C    = ws;              // 512*512
  float* CT   = C + 262144;      // 512*512
  float* W2T  = CT + 262144;     // 512*512
  float* W1T  = W2T + 262144;    // 512*64
  float* W3T  = W1T + 32768;     // 64*512
  float* w3s  = W3T + 32768;     // 512

  kpre<<<145, 256, 0, stream>>>(W1, W3, W2, C, CT, W2T, W1T, W3T, w3s);
  kfused<<<256, 512, 0, stream>>>(X, tt, beta, W1, b1, W2, b2, W3, b3,
                                  C, CT, W2T, W1T, W3T, w3s, out);
}